// Round 2
// baseline (798.870 us; speedup 1.0000x reference)
//
#include <hip/hip_runtime.h>

// ViTWarpFWarp: forward bilinear-gaussian splat.
// R4: entry-parallel fused gather.
//   - img transposed to (N,HW,C): contributor reads are 512B contiguous
//   - count/scan/fill build per-target contributor lists, entry packs
//     {s | pixel-in-tile<<20, w} so gather never touches per-pixel counts
//   - gather_fused: per block = 64 pixels x 128 ch. Entries for the tile are
//     one contiguous range -> staged into LDS in bulk (coalesced, padded with
//     zero-weight entries). 8 groups of 32 lanes each walk a contiguous span
//     entry-by-entry with a depth-4 load pipeline (independent img loads),
//     run-accumulate in registers, flush via LDS float atomics into a
//     swizzled tile, then write out_img AND out_ones coalesced in (C,HW).
// Falls back to R1 atomic path if ws_size too small.

constexpr int N_ = 4, C_ = 128, H_ = 216, W_ = 384;
constexpr int HW    = H_ * W_;            // 82944
constexpr int TOTAL = N_ * C_ * HW;       // 42467328
constexpr int PIX   = N_ * HW;            // 331776
constexpr int SCAN_BLOCKS = PIX / 256;    // 1296
constexpr int PTILE = 64;                 // pixels per gather block
constexpr int GATHER_BLOCKS = PIX / PTILE;
constexpr int ECHUNK = 512;               // staged entries per step

// ---------------- workspace layout (4-byte elements) ----------------
// [0, T)            imgT   (N,HW,C)
// [T, +PIX)         counts (uint)
// [.. +PIX)         cursor (uint)
// [.. +PIX)         offs   (uint)  block-local exclusive scan
// [.. +4096)        bs     (uint)  block sums -> exclusive scanned
// [.. +8*PIX)       entries(uint2) {s | pl<<20, w bits}, capacity 4*PIX
constexpr size_t OFF_IMGT   = 0;
constexpr size_t OFF_COUNTS = (size_t)TOTAL;
constexpr size_t OFF_CURSOR = OFF_COUNTS + PIX;
constexpr size_t OFF_OFFS   = OFF_CURSOR + PIX;
constexpr size_t OFF_BS     = OFF_OFFS + PIX;
constexpr size_t OFF_ENT    = OFF_BS + 4096;      // even -> uint2 aligned
constexpr size_t WS_ELEMS   = OFF_ENT + 8ull * PIX;
constexpr size_t WS_BYTES   = WS_ELEMS * 4;

// ---------------- helpers ----------------
__device__ inline void corner_math(float fx, float fy, int& ifx, int& ify,
                                   float& ex0, float& ex1, float& ey0, float& ey1) {
    float fx1 = floorf(fx), fy1 = floorf(fy);
    float dx = fx - fx1, dy = fy - fy1;
    ifx = (int)fx1; ify = (int)fy1;
    ex0 = __expf(-dx * dx);
    ex1 = __expf(-(dx - 1.f) * (dx - 1.f));
    ey0 = __expf(-dy * dy);
    ey1 = __expf(-(dy - 1.f) * (dy - 1.f));
}

// ---------------- pass 0: transpose img (C,HW) -> (HW,C) per batch ----------
__global__ __launch_bounds__(256) void transpose_fwd_k(const float* __restrict__ img,
                                                       float* __restrict__ imgT) {
    __shared__ float tile[32][33];
    int n   = blockIdx.z;
    int hw0 = blockIdx.x * 32;
    int c0  = blockIdx.y * 32;
    const float* src = img  + (size_t)n * C_ * HW;
    float*       dst = imgT + (size_t)n * HW * C_;
    int tx = threadIdx.x, ty = threadIdx.y;
#pragma unroll
    for (int r = 0; r < 32; r += 8)
        tile[ty + r][tx] = src[(size_t)(c0 + ty + r) * HW + hw0 + tx];
    __syncthreads();
#pragma unroll
    for (int r = 0; r < 32; r += 8)
        dst[(size_t)(hw0 + ty + r) * C_ + c0 + tx] = tile[tx][ty + r];
}

// ---------------- pass 1: count contributors per target ----------------
__global__ __launch_bounds__(256) void count_k(const float* __restrict__ flo,
                                               unsigned int* __restrict__ counts) {
    int idx = blockIdx.x * 256 + threadIdx.x;   // over PIX
    if (idx >= PIX) return;
    int s = idx % HW, n = idx / HW;
    int h = s / W_, w = s % W_;
    float fy = flo[(n * 2 + 0) * HW + s];
    float fx = flo[(n * 2 + 1) * HW + s];
    int ifx, ify; float ex0, ex1, ey0, ey1;
    corner_math(fx, fy, ifx, ify, ex0, ex1, ey0, ey1);
    int ix = h + ifx, iy = w + ify;
    unsigned int* base = counts + (size_t)n * HW;
    bool bx0 = (unsigned)ix       < (unsigned)H_;
    bool bx1 = (unsigned)(ix + 1) < (unsigned)H_;
    bool by0 = (unsigned)iy       < (unsigned)W_;
    bool by1 = (unsigned)(iy + 1) < (unsigned)W_;
    if (bx0 && by0) atomicAdd(base + ix * W_ + iy, 1u);
    if (bx0 && by1) atomicAdd(base + ix * W_ + iy + 1, 1u);
    if (bx1 && by0) atomicAdd(base + (ix + 1) * W_ + iy, 1u);
    if (bx1 && by1) atomicAdd(base + (ix + 1) * W_ + iy + 1, 1u);
}

// ---------------- pass 2: exclusive scan (2 kernels; add folded into users) --
__global__ __launch_bounds__(256) void scan_local_k(const unsigned int* __restrict__ counts,
                                                    unsigned int* __restrict__ offs,
                                                    unsigned int* __restrict__ bs) {
    __shared__ unsigned int tmp[256];
    int tid = threadIdx.x;
    int i = blockIdx.x * 256 + tid;
    unsigned int v = counts[i];
    tmp[tid] = v;
    __syncthreads();
    for (int off = 1; off < 256; off <<= 1) {
        unsigned int t = (tid >= off) ? tmp[tid - off] : 0u;
        __syncthreads();
        tmp[tid] += t;
        __syncthreads();
    }
    offs[i] = tmp[tid] - v;                 // exclusive within block
    if (tid == 255) bs[blockIdx.x] = tmp[tid];
}

__global__ __launch_bounds__(256) void scan_bs_k(unsigned int* __restrict__ bs) {
    __shared__ unsigned int tmp[256];
    constexpr int IT = 6;                    // 256*6 = 1536 >= 1296
    int tid = threadIdx.x;
    unsigned int v[IT]; unsigned int sum = 0;
#pragma unroll
    for (int i = 0; i < IT; ++i) {
        int j = tid * IT + i;
        v[i] = (j < SCAN_BLOCKS) ? bs[j] : 0u;
        sum += v[i];
    }
    tmp[tid] = sum;
    __syncthreads();
    for (int off = 1; off < 256; off <<= 1) {
        unsigned int t = (tid >= off) ? tmp[tid - off] : 0u;
        __syncthreads();
        tmp[tid] += t;
        __syncthreads();
    }
    unsigned int run = tmp[tid] - sum;       // exclusive
#pragma unroll
    for (int i = 0; i < IT; ++i) {
        int j = tid * IT + i;
        if (j < SCAN_BLOCKS) { unsigned int old = v[i]; bs[j] = run; run += old; }
    }
}

// ---------------- pass 3: fill entries (adds bs itself, packs pixel-in-tile) -
__global__ __launch_bounds__(256) void fill_k(const float* __restrict__ flo,
                                              const unsigned int* __restrict__ offs,
                                              const unsigned int* __restrict__ bs,
                                              unsigned int* __restrict__ cursor,
                                              uint2* __restrict__ entries) {
    int idx = blockIdx.x * 256 + threadIdx.x;
    if (idx >= PIX) return;
    int s = idx % HW, n = idx / HW;
    int h = s / W_, w = s % W_;
    float fy = flo[(n * 2 + 0) * HW + s];
    float fx = flo[(n * 2 + 1) * HW + s];
    int ifx, ify; float ex0, ex1, ey0, ey1;
    corner_math(fx, fy, ifx, ify, ex0, ex1, ey0, ey1);
    int ix = h + ifx, iy = w + ify;
    bool bx[2] = { (unsigned)ix < (unsigned)H_, (unsigned)(ix + 1) < (unsigned)H_ };
    bool by[2] = { (unsigned)iy < (unsigned)W_, (unsigned)(iy + 1) < (unsigned)W_ };
    float exw[2] = { ex0, ex1 }, eyw[2] = { ey0, ey1 };
#pragma unroll
    for (int a = 0; a < 2; ++a) {
#pragma unroll
        for (int b = 0; b < 2; ++b) {
            if (bx[a] && by[b]) {
                int t = n * HW + (ix + a) * W_ + (iy + b);
                unsigned int slot = atomicAdd(cursor + t, 1u);
                unsigned int e = offs[t] + bs[t >> 8] + slot;
                // s fits 17 bits (HW=82944); pixel-in-tile = t & 63 in bits 20+
                entries[e] = make_uint2((unsigned int)s | ((unsigned int)(t & 63) << 20),
                                        __float_as_uint(exw[a] * eyw[b]));
            }
        }
    }
}

// ---------------- pass 4: entry-parallel fused gather ----------------
// Block = 64 consecutive output pixels (tile), 256 threads = 8 groups x 32.
// 1) zero swizzled tile[128ch][64px] + wsum[64] in LDS
// 2) stage the tile's contiguous entry range into LDS (ECHUNK at a time,
//    padded with {0,0} so all bounds are uniform; zero-weight pad is harmless)
// 3) each group walks a contiguous span: depth-4 pipeline of
//    ds_read entry -> independent global img float4 load; run-accumulate in
//    regs while pixel id unchanged; flush via ds_add_f32 atomics
// 4) epilogue: swizzled b128 reads, coalesced float4 stores of both outputs
__global__ __launch_bounds__(256) void gather_fused_k(const float* __restrict__ imgT,
                                                      const unsigned int* __restrict__ counts,
                                                      const unsigned int* __restrict__ offs,
                                                      const unsigned int* __restrict__ bs,
                                                      const uint2* __restrict__ entries,
                                                      float* __restrict__ out_img,
                                                      float* __restrict__ out_ones) {
    __shared__ float tile[C_ * PTILE];       // 32 KB, [c][slot*4+pr] swizzled
    __shared__ float wsum_lds[PTILE];
    __shared__ uint2 ent_lds[ECHUNK];        // 4 KB staging

    int tid = threadIdx.x;
    int g   = tid >> 5;                      // group 0..7
    int cg  = tid & 31;                      // channel group (4 ch)
    int bt  = blockIdx.x;
    int n   = bt / (HW / PTILE);
    int p0  = (bt % (HW / PTILE)) * PTILE;
    const float4* srcBase = (const float4*)(imgT + (size_t)n * HW * C_);

    // ---- zero tile + wsum ----
    {
        float4 z = make_float4(0.f, 0.f, 0.f, 0.f);
        float4* t4 = (float4*)tile;
#pragma unroll
        for (int i = 0; i < 8; ++i) t4[tid + 256 * i] = z;
        if (tid < 16) ((float4*)wsum_lds)[tid] = z;
    }

    // ---- entry range for this tile (uniform across block) ----
    int t0 = n * HW + p0;
    int t63 = t0 + 63;
    unsigned int E_base = offs[t0]  + bs[t0 >> 8];
    unsigned int E_end  = offs[t63] + bs[t63 >> 8] + counts[t63];

    float4 acc = make_float4(0.f, 0.f, 0.f, 0.f);
    float  wacc = 0.f;
    int    cur_p = -1;

    auto flush = [&]() {
        if (cur_p >= 0) {
            int p4 = cur_p >> 2, pr = cur_p & 3;
            int basei = (p4 ^ (cg & 15)) * 4 + pr;   // swizzle matches epilogue
            atomicAdd(&tile[(4 * cg + 0) * PTILE + basei], acc.x);
            atomicAdd(&tile[(4 * cg + 1) * PTILE + basei], acc.y);
            atomicAdd(&tile[(4 * cg + 2) * PTILE + basei], acc.z);
            atomicAdd(&tile[(4 * cg + 3) * PTILE + basei], acc.w);
            if (cg == 0) atomicAdd(&wsum_lds[cur_p], wacc);
        }
        acc = make_float4(0.f, 0.f, 0.f, 0.f);
        wacc = 0.f;
    };

#define PROC(E, V)                                            \
    {                                                         \
        int p_ = (int)((E).x >> 20);                          \
        if (p_ != cur_p) { flush(); cur_p = p_; }             \
        float w_ = __uint_as_float((E).y);                    \
        acc.x += w_ * (V).x; acc.y += w_ * (V).y;             \
        acc.z += w_ * (V).z; acc.w += w_ * (V).w;             \
        wacc  += w_;                                          \
    }

    for (unsigned int cb = E_base; cb < E_end; cb += ECHUNK) {
        unsigned int m  = min((unsigned int)ECHUNK, E_end - cb);
        unsigned int mp = (m + 31u) & ~31u;      // pad to x32 -> span x4
        __syncthreads();                         // prior chunk fully consumed
        for (unsigned int i = tid; i < mp; i += 256)
            ent_lds[i] = (i < m) ? entries[cb + i] : make_uint2(0u, 0u);
        __syncthreads();
        unsigned int span = mp >> 3;             // per group, multiple of 4
        unsigned int b = g * span;
        for (unsigned int i = 0; i < span; i += 4) {
            uint2 E0 = ent_lds[b + i + 0];
            uint2 E1 = ent_lds[b + i + 1];
            uint2 E2 = ent_lds[b + i + 2];
            uint2 E3 = ent_lds[b + i + 3];
            float4 V0 = srcBase[(size_t)(E0.x & 0xFFFFFu) * (C_ / 4) + cg];
            float4 V1 = srcBase[(size_t)(E1.x & 0xFFFFFu) * (C_ / 4) + cg];
            float4 V2 = srcBase[(size_t)(E2.x & 0xFFFFFu) * (C_ / 4) + cg];
            float4 V3 = srcBase[(size_t)(E3.x & 0xFFFFFu) * (C_ / 4) + cg];
            PROC(E0, V0); PROC(E1, V1); PROC(E2, V2); PROC(E3, V3);
        }
    }
    flush();
#undef PROC
    __syncthreads();

    // ---- epilogue: coalesced stores of both outputs ----
    int p4    = tid & 15;                    // float4 column within tile
    int cbase = tid >> 4;                    // 0..15
    float4 wv = ((const float4*)wsum_lds)[p4];
#pragma unroll
    for (int i = 0; i < 8; ++i) {
        int c    = cbase + 16 * i;
        int slot = p4 ^ ((c >> 2) & 15);
        float4 v = *(const float4*)&tile[c * PTILE + slot * 4];
        size_t o = ((size_t)(n * C_ + c)) * HW + p0 + p4 * 4;
        *(float4*)(out_img  + o) = v;
        *(float4*)(out_ones + o) = wv;
    }
}

// ================= R1 fallback (atomic scatter) =================
__global__ __launch_bounds__(256) void fb_ones_scatter_k(const float* __restrict__ flo,
                                                         float* __restrict__ out_ones) {
    int idx = blockIdx.x * 256 + threadIdx.x;
    if (idx >= PIX) return;
    int w = idx % W_; int hn = idx / W_; int h = hn % H_; int n = hn / H_;
    float fy = flo[(n * 2 + 0) * HW + h * W_ + w];
    float fx = flo[(n * 2 + 1) * HW + h * W_ + w];
    int ifx, ify; float ex0, ex1, ey0, ey1;
    corner_math(fx, fy, ifx, ify, ex0, ex1, ey0, ey1);
    int ix = h + ifx, iy = w + ify;
    float* plane = out_ones + (size_t)n * C_ * HW;
    if ((unsigned)ix < (unsigned)H_ && (unsigned)iy < (unsigned)W_) atomicAdd(plane + ix * W_ + iy, ex0 * ey0);
    if ((unsigned)ix < (unsigned)H_ && (unsigned)(iy+1) < (unsigned)W_) atomicAdd(plane + ix * W_ + iy + 1, ex0 * ey1);
    if ((unsigned)(ix+1) < (unsigned)H_ && (unsigned)iy < (unsigned)W_) atomicAdd(plane + (ix+1) * W_ + iy, ex1 * ey0);
    if ((unsigned)(ix+1) < (unsigned)H_ && (unsigned)(iy+1) < (unsigned)W_) atomicAdd(plane + (ix+1) * W_ + iy + 1, ex1 * ey1);
}

__global__ __launch_bounds__(256) void fb_img_scatter_k(const float* __restrict__ img,
                                                        const float* __restrict__ flo,
                                                        float* __restrict__ out_img) {
    int idx = blockIdx.x * 256 + threadIdx.x;
    if (idx >= TOTAL) return;
    int w = idx % W_; int rem = idx / W_; int h = rem % H_; rem /= H_;
    int c = rem % C_; int n = rem / C_;
    float fy = flo[(n * 2 + 0) * HW + h * W_ + w];
    float fx = flo[(n * 2 + 1) * HW + h * W_ + w];
    int ifx, ify; float ex0, ex1, ey0, ey1;
    corner_math(fx, fy, ifx, ify, ex0, ex1, ey0, ey1);
    int ix = h + ifx, iy = w + ify;
    float v = img[idx];
    float* plane = out_img + (size_t)(n * C_ + c) * HW;
    if ((unsigned)ix < (unsigned)H_ && (unsigned)iy < (unsigned)W_) atomicAdd(plane + ix * W_ + iy, v * ex0 * ey0);
    if ((unsigned)ix < (unsigned)H_ && (unsigned)(iy+1) < (unsigned)W_) atomicAdd(plane + ix * W_ + iy + 1, v * ex0 * ey1);
    if ((unsigned)(ix+1) < (unsigned)H_ && (unsigned)iy < (unsigned)W_) atomicAdd(plane + (ix+1) * W_ + iy, v * ex1 * ey0);
    if ((unsigned)(ix+1) < (unsigned)H_ && (unsigned)(iy+1) < (unsigned)W_) atomicAdd(plane + (ix+1) * W_ + iy + 1, v * ex1 * ey1);
}

__global__ __launch_bounds__(256) void fb_ones_bcast_k(float* __restrict__ out_ones) {
    constexpr int HW4 = HW / 4;
    constexpr int TOT = N_ * (C_ - 1) * HW4;
    int idx = blockIdx.x * 256 + threadIdx.x;
    if (idx >= TOT) return;
    int p = idx % HW4; int cn = idx / HW4;
    int c = 1 + cn % (C_ - 1); int n = cn / (C_ - 1);
    const float4* src = (const float4*)(out_ones + (size_t)n * C_ * HW);
    float4*       dst = (float4*)(out_ones + ((size_t)n * C_ + c) * HW);
    dst[p] = src[p];
}

// ================= launch =================
extern "C" void kernel_launch(void* const* d_in, const int* in_sizes, int n_in,
                              void* d_out, int out_size, void* d_ws, size_t ws_size,
                              hipStream_t stream) {
    const float* img = (const float*)d_in[0];
    const float* flo = (const float*)d_in[1];
    float* out      = (float*)d_out;
    float* out_img  = out;
    float* out_ones = out + (size_t)TOTAL;

    if (ws_size < WS_BYTES) {
        // fallback: R1 atomic path
        hipMemsetAsync(out_img, 0, (size_t)TOTAL * sizeof(float), stream);
        for (int n = 0; n < N_; ++n)
            hipMemsetAsync(out_ones + (size_t)n * C_ * HW, 0, HW * sizeof(float), stream);
        fb_ones_scatter_k<<<(PIX + 255) / 256, 256, 0, stream>>>(flo, out_ones);
        fb_img_scatter_k<<<(TOTAL + 255) / 256, 256, 0, stream>>>(img, flo, out_img);
        fb_ones_bcast_k<<<(N_ * (C_ - 1) * (HW / 4) + 255) / 256, 256, 0, stream>>>(out_ones);
        return;
    }

    float* ws = (float*)d_ws;
    float*        imgT    = ws + OFF_IMGT;
    unsigned int* counts  = (unsigned int*)(ws + OFF_COUNTS);
    unsigned int* cursor  = (unsigned int*)(ws + OFF_CURSOR);
    unsigned int* offs    = (unsigned int*)(ws + OFF_OFFS);
    unsigned int* bs      = (unsigned int*)(ws + OFF_BS);
    uint2*        entries = (uint2*)(ws + OFF_ENT);

    // zero counts+cursor (contiguous)
    hipMemsetAsync(counts, 0, 2ull * PIX * sizeof(unsigned int), stream);

    dim3 tb(32, 8);
    transpose_fwd_k<<<dim3(HW / 32, C_ / 32, N_), tb, 0, stream>>>(img, imgT);
    count_k<<<SCAN_BLOCKS, 256, 0, stream>>>(flo, counts);
    scan_local_k<<<SCAN_BLOCKS, 256, 0, stream>>>(counts, offs, bs);
    scan_bs_k<<<1, 256, 0, stream>>>(bs);
    fill_k<<<SCAN_BLOCKS, 256, 0, stream>>>(flo, offs, bs, cursor, entries);
    gather_fused_k<<<GATHER_BLOCKS, 256, 0, stream>>>(imgT, counts, offs, bs,
                                                      entries, out_img, out_ones);
}

// Round 3
// 716.939 us; speedup vs baseline: 1.1143x; 1.1143x over previous
//
#include <hip/hip_runtime.h>

// ViTWarpFWarp: forward bilinear-gaussian splat.
// R5: pixel-parallel fused gather with loop-nest swap for MLP.
//   - img transposed to (N,HW,C): contributor reads are 512B contiguous
//   - count/scan/fill build per-target contributor lists (uint2 {s|pl<<20, w})
//   - gather_fused: block = 64 pixels x 128 ch; 8 groups x 32 lanes; each
//     thread owns 8 pixels x 4 channels. Outer loop over entry rank (bound =
//     max k of the thread's 8 pixels), inner UNROLLED loop over the 8 pixels:
//     8 independent entry loads + 8 independent img float4 loads in flight
//     per iteration, predicated accumulate (no branches, no atomics).
//     Epilogue: swizzled LDS transpose -> coalesced stores of out_img AND
//     out_ones in (C,HW). (R3 epilogue, verified.)
// Falls back to R1 atomic path if ws_size too small.

constexpr int N_ = 4, C_ = 128, H_ = 216, W_ = 384;
constexpr int HW    = H_ * W_;            // 82944
constexpr int TOTAL = N_ * C_ * HW;       // 42467328
constexpr int PIX   = N_ * HW;            // 331776
constexpr int SCAN_BLOCKS = PIX / 256;    // 1296
constexpr int PTILE = 64;                 // pixels per gather block
constexpr int GATHER_BLOCKS = PIX / PTILE;

// ---------------- workspace layout (4-byte elements) ----------------
// [0, T)            imgT   (N,HW,C)
// [T, +PIX)         counts (uint)
// [.. +PIX)         cursor (uint)
// [.. +PIX)         offs   (uint)  block-local exclusive scan
// [.. +4096)        bs     (uint)  block sums -> exclusive scanned
// [.. +8*PIX+16)    entries(uint2) {s | pl<<20, w bits}, cap 4*PIX + slack
constexpr size_t OFF_IMGT   = 0;
constexpr size_t OFF_COUNTS = (size_t)TOTAL;
constexpr size_t OFF_CURSOR = OFF_COUNTS + PIX;
constexpr size_t OFF_OFFS   = OFF_CURSOR + PIX;
constexpr size_t OFF_BS     = OFF_OFFS + PIX;
constexpr size_t OFF_ENT    = OFF_BS + 4096;      // even -> uint2 aligned
constexpr size_t WS_ELEMS   = OFF_ENT + 8ull * PIX + 16;  // +slack for clamp
constexpr size_t WS_BYTES   = WS_ELEMS * 4;

// ---------------- helpers ----------------
__device__ inline void corner_math(float fx, float fy, int& ifx, int& ify,
                                   float& ex0, float& ex1, float& ey0, float& ey1) {
    float fx1 = floorf(fx), fy1 = floorf(fy);
    float dx = fx - fx1, dy = fy - fy1;
    ifx = (int)fx1; ify = (int)fy1;
    ex0 = __expf(-dx * dx);
    ex1 = __expf(-(dx - 1.f) * (dx - 1.f));
    ey0 = __expf(-dy * dy);
    ey1 = __expf(-(dy - 1.f) * (dy - 1.f));
}

// ---------------- pass 0: transpose img (C,HW) -> (HW,C) per batch ----------
__global__ __launch_bounds__(256) void transpose_fwd_k(const float* __restrict__ img,
                                                       float* __restrict__ imgT) {
    __shared__ float tile[32][33];
    int n   = blockIdx.z;
    int hw0 = blockIdx.x * 32;
    int c0  = blockIdx.y * 32;
    const float* src = img  + (size_t)n * C_ * HW;
    float*       dst = imgT + (size_t)n * HW * C_;
    int tx = threadIdx.x, ty = threadIdx.y;
#pragma unroll
    for (int r = 0; r < 32; r += 8)
        tile[ty + r][tx] = src[(size_t)(c0 + ty + r) * HW + hw0 + tx];
    __syncthreads();
#pragma unroll
    for (int r = 0; r < 32; r += 8)
        dst[(size_t)(hw0 + ty + r) * C_ + c0 + tx] = tile[tx][ty + r];
}

// ---------------- pass 1: count contributors per target ----------------
__global__ __launch_bounds__(256) void count_k(const float* __restrict__ flo,
                                               unsigned int* __restrict__ counts) {
    int idx = blockIdx.x * 256 + threadIdx.x;   // over PIX
    if (idx >= PIX) return;
    int s = idx % HW, n = idx / HW;
    int h = s / W_, w = s % W_;
    float fy = flo[(n * 2 + 0) * HW + s];
    float fx = flo[(n * 2 + 1) * HW + s];
    int ifx, ify; float ex0, ex1, ey0, ey1;
    corner_math(fx, fy, ifx, ify, ex0, ex1, ey0, ey1);
    int ix = h + ifx, iy = w + ify;
    unsigned int* base = counts + (size_t)n * HW;
    bool bx0 = (unsigned)ix       < (unsigned)H_;
    bool bx1 = (unsigned)(ix + 1) < (unsigned)H_;
    bool by0 = (unsigned)iy       < (unsigned)W_;
    bool by1 = (unsigned)(iy + 1) < (unsigned)W_;
    if (bx0 && by0) atomicAdd(base + ix * W_ + iy, 1u);
    if (bx0 && by1) atomicAdd(base + ix * W_ + iy + 1, 1u);
    if (bx1 && by0) atomicAdd(base + (ix + 1) * W_ + iy, 1u);
    if (bx1 && by1) atomicAdd(base + (ix + 1) * W_ + iy + 1, 1u);
}

// ---------------- pass 2: exclusive scan (2 kernels; add folded into users) --
__global__ __launch_bounds__(256) void scan_local_k(const unsigned int* __restrict__ counts,
                                                    unsigned int* __restrict__ offs,
                                                    unsigned int* __restrict__ bs) {
    __shared__ unsigned int tmp[256];
    int tid = threadIdx.x;
    int i = blockIdx.x * 256 + tid;
    unsigned int v = counts[i];
    tmp[tid] = v;
    __syncthreads();
    for (int off = 1; off < 256; off <<= 1) {
        unsigned int t = (tid >= off) ? tmp[tid - off] : 0u;
        __syncthreads();
        tmp[tid] += t;
        __syncthreads();
    }
    offs[i] = tmp[tid] - v;                 // exclusive within block
    if (tid == 255) bs[blockIdx.x] = tmp[tid];
}

__global__ __launch_bounds__(256) void scan_bs_k(unsigned int* __restrict__ bs) {
    __shared__ unsigned int tmp[256];
    constexpr int IT = 6;                    // 256*6 = 1536 >= 1296
    int tid = threadIdx.x;
    unsigned int v[IT]; unsigned int sum = 0;
#pragma unroll
    for (int i = 0; i < IT; ++i) {
        int j = tid * IT + i;
        v[i] = (j < SCAN_BLOCKS) ? bs[j] : 0u;
        sum += v[i];
    }
    tmp[tid] = sum;
    __syncthreads();
    for (int off = 1; off < 256; off <<= 1) {
        unsigned int t = (tid >= off) ? tmp[tid - off] : 0u;
        __syncthreads();
        tmp[tid] += t;
        __syncthreads();
    }
    unsigned int run = tmp[tid] - sum;       // exclusive
#pragma unroll
    for (int i = 0; i < IT; ++i) {
        int j = tid * IT + i;
        if (j < SCAN_BLOCKS) { unsigned int old = v[i]; bs[j] = run; run += old; }
    }
}

// ---------------- pass 3: fill entries (adds bs itself) ----------------
__global__ __launch_bounds__(256) void fill_k(const float* __restrict__ flo,
                                              const unsigned int* __restrict__ offs,
                                              const unsigned int* __restrict__ bs,
                                              unsigned int* __restrict__ cursor,
                                              uint2* __restrict__ entries) {
    int idx = blockIdx.x * 256 + threadIdx.x;
    if (idx >= PIX) return;
    int s = idx % HW, n = idx / HW;
    int h = s / W_, w = s % W_;
    float fy = flo[(n * 2 + 0) * HW + s];
    float fx = flo[(n * 2 + 1) * HW + s];
    int ifx, ify; float ex0, ex1, ey0, ey1;
    corner_math(fx, fy, ifx, ify, ex0, ex1, ey0, ey1);
    int ix = h + ifx, iy = w + ify;
    bool bx[2] = { (unsigned)ix < (unsigned)H_, (unsigned)(ix + 1) < (unsigned)H_ };
    bool by[2] = { (unsigned)iy < (unsigned)W_, (unsigned)(iy + 1) < (unsigned)W_ };
    float exw[2] = { ex0, ex1 }, eyw[2] = { ey0, ey1 };
#pragma unroll
    for (int a = 0; a < 2; ++a) {
#pragma unroll
        for (int b = 0; b < 2; ++b) {
            if (bx[a] && by[b]) {
                int t = n * HW + (ix + a) * W_ + (iy + b);
                unsigned int slot = atomicAdd(cursor + t, 1u);
                unsigned int e = offs[t] + bs[t >> 8] + slot;
                // s fits 17 bits (HW=82944); keep pl in bits 20+ (unused here)
                entries[e] = make_uint2((unsigned int)s | ((unsigned int)(t & 63) << 20),
                                        __float_as_uint(exw[a] * eyw[b]));
            }
        }
    }
}

// ---------------- pass 4: fused gather, loop-nest swapped ----------------
// Block = 64 consecutive output pixels, 256 threads = 8 groups x 32 lanes.
// Thread (g=pl, cg) owns pixels {si*8+pl} for si=0..7, channels 4cg..4cg+3.
// Outer loop it=0..kmax-1 (kmax = max k over the thread's 8 pixels, uniform
// within the 32-lane group); inner unrolled si-loop issues 8 independent
// entry loads then 8 independent img loads -> high MLP, zero branches.
// Out-of-range its: clamped index (always valid entry), weight forced to 0.
__global__ __launch_bounds__(256) void gather_fused_k(const float* __restrict__ imgT,
                                                      const unsigned int* __restrict__ counts,
                                                      const unsigned int* __restrict__ offs,
                                                      const unsigned int* __restrict__ bs,
                                                      const uint2* __restrict__ entries,
                                                      float* __restrict__ out_img,
                                                      float* __restrict__ out_ones) {
    __shared__ float tile[C_ * PTILE];       // 32 KB, [c][slot*4+pr] swizzled
    __shared__ float wsum_lds[PTILE];
    __shared__ unsigned int ebase_lds[PTILE];
    __shared__ unsigned int k_lds[PTILE];

    int tid = threadIdx.x;
    int pl  = tid >> 5;                      // 0..7 pixel-in-subtile
    int cg  = tid & 31;                      // channel group (4 ch)
    int bt  = blockIdx.x;
    int n   = bt / (HW / PTILE);
    int p0  = (bt % (HW / PTILE)) * PTILE;
    int t0  = n * HW + p0;
    const float4* srcBase = (const float4*)(imgT + (size_t)n * HW * C_);

    // ---- stage per-pixel meta ----
    if (tid < PTILE) {
        int t = t0 + tid;
        ebase_lds[tid] = offs[t] + bs[t >> 8];
        k_lds[tid]     = counts[t];
    }
    __syncthreads();

    unsigned int eb[8], kk[8];
    unsigned int kmax = 0;
#pragma unroll
    for (int si = 0; si < 8; ++si) {
        int p = si * 8 + pl;
        eb[si] = ebase_lds[p];
        kk[si] = k_lds[p];
        kmax = max(kmax, kk[si]);
    }

    float4 acc[8];
    float  ws[8];
#pragma unroll
    for (int si = 0; si < 8; ++si) { acc[si] = make_float4(0.f,0.f,0.f,0.f); ws[si] = 0.f; }

    for (unsigned int it = 0; it < kmax; ++it) {
        uint2 E[8];
#pragma unroll
        for (int si = 0; si < 8; ++si) {
            unsigned int jc = min(it, max(kk[si], 1u) - 1u);   // always valid
            E[si] = entries[eb[si] + jc];
        }
        float4 V[8];
#pragma unroll
        for (int si = 0; si < 8; ++si)
            V[si] = srcBase[(size_t)(E[si].x & 0xFFFFFu) * (C_ / 4) + cg];
#pragma unroll
        for (int si = 0; si < 8; ++si) {
            float w = (it < kk[si]) ? __uint_as_float(E[si].y) : 0.f;
            acc[si].x += w * V[si].x; acc[si].y += w * V[si].y;
            acc[si].z += w * V[si].z; acc[si].w += w * V[si].w;
            ws[si]    += w;
        }
    }

    // ---- Phase B: regs -> swizzled LDS (each (c,p) written exactly once) ----
#pragma unroll
    for (int si = 0; si < 8; ++si) {
        int p  = si * 8 + pl;
        if (cg == 0) wsum_lds[p] = ws[si];
        int p4 = p >> 2, pr = p & 3;
        float av[4] = { acc[si].x, acc[si].y, acc[si].z, acc[si].w };
#pragma unroll
        for (int jj = 0; jj < 4; ++jj) {
            int c    = 4 * cg + jj;
            int slot = p4 ^ ((c >> 2) & 15);
            tile[c * PTILE + slot * 4 + pr] = av[jj];
        }
    }
    __syncthreads();

    // ---- Phase C: coalesced stores of both outputs ----
    int p4    = tid & 15;                    // float4 column within tile
    int cbase = tid >> 4;                    // 0..15
    float4 wv = ((const float4*)wsum_lds)[p4];
#pragma unroll
    for (int i = 0; i < 8; ++i) {
        int c    = cbase + 16 * i;
        int slot = p4 ^ ((c >> 2) & 15);
        float4 v = *(const float4*)&tile[c * PTILE + slot * 4];
        size_t o = ((size_t)(n * C_ + c)) * HW + p0 + p4 * 4;
        *(float4*)(out_img  + o) = v;
        *(float4*)(out_ones + o) = wv;
    }
}

// ================= R1 fallback (atomic scatter) =================
__global__ __launch_bounds__(256) void fb_ones_scatter_k(const float* __restrict__ flo,
                                                         float* __restrict__ out_ones) {
    int idx = blockIdx.x * 256 + threadIdx.x;
    if (idx >= PIX) return;
    int w = idx % W_; int hn = idx / W_; int h = hn % H_; int n = hn / H_;
    float fy = flo[(n * 2 + 0) * HW + h * W_ + w];
    float fx = flo[(n * 2 + 1) * HW + h * W_ + w];
    int ifx, ify; float ex0, ex1, ey0, ey1;
    corner_math(fx, fy, ifx, ify, ex0, ex1, ey0, ey1);
    int ix = h + ifx, iy = w + ify;
    float* plane = out_ones + (size_t)n * C_ * HW;
    if ((unsigned)ix < (unsigned)H_ && (unsigned)iy < (unsigned)W_) atomicAdd(plane + ix * W_ + iy, ex0 * ey0);
    if ((unsigned)ix < (unsigned)H_ && (unsigned)(iy+1) < (unsigned)W_) atomicAdd(plane + ix * W_ + iy + 1, ex0 * ey1);
    if ((unsigned)(ix+1) < (unsigned)H_ && (unsigned)iy < (unsigned)W_) atomicAdd(plane + (ix+1) * W_ + iy, ex1 * ey0);
    if ((unsigned)(ix+1) < (unsigned)H_ && (unsigned)(iy+1) < (unsigned)W_) atomicAdd(plane + (ix+1) * W_ + iy + 1, ex1 * ey1);
}

__global__ __launch_bounds__(256) void fb_img_scatter_k(const float* __restrict__ img,
                                                        const float* __restrict__ flo,
                                                        float* __restrict__ out_img) {
    int idx = blockIdx.x * 256 + threadIdx.x;
    if (idx >= TOTAL) return;
    int w = idx % W_; int rem = idx / W_; int h = rem % H_; rem /= H_;
    int c = rem % C_; int n = rem / C_;
    float fy = flo[(n * 2 + 0) * HW + h * W_ + w];
    float fx = flo[(n * 2 + 1) * HW + h * W_ + w];
    int ifx, ify; float ex0, ex1, ey0, ey1;
    corner_math(fx, fy, ifx, ify, ex0, ex1, ey0, ey1);
    int ix = h + ifx, iy = w + ify;
    float v = img[idx];
    float* plane = out_img + (size_t)(n * C_ + c) * HW;
    if ((unsigned)ix < (unsigned)H_ && (unsigned)iy < (unsigned)W_) atomicAdd(plane + ix * W_ + iy, v * ex0 * ey0);
    if ((unsigned)ix < (unsigned)H_ && (unsigned)(iy+1) < (unsigned)W_) atomicAdd(plane + ix * W_ + iy + 1, v * ex0 * ey1);
    if ((unsigned)(ix+1) < (unsigned)H_ && (unsigned)iy < (unsigned)W_) atomicAdd(plane + (ix+1) * W_ + iy, v * ex1 * ey0);
    if ((unsigned)(ix+1) < (unsigned)H_ && (unsigned)(iy+1) < (unsigned)W_) atomicAdd(plane + (ix+1) * W_ + iy + 1, v * ex1 * ey1);
}

__global__ __launch_bounds__(256) void fb_ones_bcast_k(float* __restrict__ out_ones) {
    constexpr int HW4 = HW / 4;
    constexpr int TOT = N_ * (C_ - 1) * HW4;
    int idx = blockIdx.x * 256 + threadIdx.x;
    if (idx >= TOT) return;
    int p = idx % HW4; int cn = idx / HW4;
    int c = 1 + cn % (C_ - 1); int n = cn / (C_ - 1);
    const float4* src = (const float4*)(out_ones + (size_t)n * C_ * HW);
    float4*       dst = (float4*)(out_ones + ((size_t)n * C_ + c) * HW);
    dst[p] = src[p];
}

// ================= launch =================
extern "C" void kernel_launch(void* const* d_in, const int* in_sizes, int n_in,
                              void* d_out, int out_size, void* d_ws, size_t ws_size,
                              hipStream_t stream) {
    const float* img = (const float*)d_in[0];
    const float* flo = (const float*)d_in[1];
    float* out      = (float*)d_out;
    float* out_img  = out;
    float* out_ones = out + (size_t)TOTAL;

    if (ws_size < WS_BYTES) {
        // fallback: R1 atomic path
        hipMemsetAsync(out_img, 0, (size_t)TOTAL * sizeof(float), stream);
        for (int n = 0; n < N_; ++n)
            hipMemsetAsync(out_ones + (size_t)n * C_ * HW, 0, HW * sizeof(float), stream);
        fb_ones_scatter_k<<<(PIX + 255) / 256, 256, 0, stream>>>(flo, out_ones);
        fb_img_scatter_k<<<(TOTAL + 255) / 256, 256, 0, stream>>>(img, flo, out_img);
        fb_ones_bcast_k<<<(N_ * (C_ - 1) * (HW / 4) + 255) / 256, 256, 0, stream>>>(out_ones);
        return;
    }

    float* ws = (float*)d_ws;
    float*        imgT    = ws + OFF_IMGT;
    unsigned int* counts  = (unsigned int*)(ws + OFF_COUNTS);
    unsigned int* cursor  = (unsigned int*)(ws + OFF_CURSOR);
    unsigned int* offs    = (unsigned int*)(ws + OFF_OFFS);
    unsigned int* bs      = (unsigned int*)(ws + OFF_BS);
    uint2*        entries = (uint2*)(ws + OFF_ENT);

    // zero counts+cursor (contiguous)
    hipMemsetAsync(counts, 0, 2ull * PIX * sizeof(unsigned int), stream);

    dim3 tb(32, 8);
    transpose_fwd_k<<<dim3(HW / 32, C_ / 32, N_), tb, 0, stream>>>(img, imgT);
    count_k<<<SCAN_BLOCKS, 256, 0, stream>>>(flo, counts);
    scan_local_k<<<SCAN_BLOCKS, 256, 0, stream>>>(counts, offs, bs);
    scan_bs_k<<<1, 256, 0, stream>>>(bs);
    fill_k<<<SCAN_BLOCKS, 256, 0, stream>>>(flo, offs, bs, cursor, entries);
    gather_fused_k<<<GATHER_BLOCKS, 256, 0, stream>>>(imgT, counts, offs, bs,
                                                      entries, out_img, out_ones);
}